// Round 1
// baseline (446.453 us; speedup 1.0000x reference)
//
#include <hip/hip_runtime.h>
#include <hip/hip_bf16.h>
#include <stdint.h>

// Problem constants (from reference)
#define S_  32
#define P_  48
#define T_  8
#define E_  64
#define H_  64
#define D1_ 512
#define D2_ 1024
#define B_  (S_*P_)        // 1536
#define M_  (S_*P_*P_)     // 73728 rows of the big GEMMs
#define K1_ 576            // T*E + H
#define KE_ 512            // T*E

typedef __attribute__((ext_vector_type(8))) short  short8;
typedef __attribute__((ext_vector_type(8))) __bf16 bf16x8;
typedef __attribute__((ext_vector_type(4))) float  f32x4;

// fp32 -> bf16 (round to nearest even), bit carrier = short
__device__ inline short f2bf(float x) {
  union { float f; unsigned u; } v; v.f = x;
  unsigned r = v.u + 0x7FFFu + ((v.u >> 16) & 1u);
  return (short)(r >> 16);
}

// async global->LDS, 16 bytes per lane (wave-uniform base + lane*16 pattern)
__device__ inline void async16(const void* g, void* l) {
  __builtin_amdgcn_global_load_lds(
      (const __attribute__((address_space(1))) void*)g,
      (__attribute__((address_space(3))) void*)l, 16, 0, 0);
}

__device__ inline f32x4 mfma16(short8 a, short8 b, f32x4 c) {
  return __builtin_amdgcn_mfma_f32_16x16x32_bf16(
      __builtin_bit_cast(bf16x8, a), __builtin_bit_cast(bf16x8, b), c, 0, 0, 0);
}

// ---------------------------------------------------------------- K0: weights -> bf16
__global__ __launch_bounds__(256) void k_cvt_w(const float* __restrict__ W1,
                                               const float* __restrict__ W2,
                                               short* __restrict__ W1b,
                                               short* __restrict__ W2b) {
  int idx = blockIdx.x * 256 + threadIdx.x;
  if (idx < D1_ * K1_) W1b[idx] = f2bf(W1[idx]);
  int idx2 = idx - D1_ * K1_;
  if (idx2 >= 0 && idx2 < D2_ * D1_) W2b[idx2] = f2bf(W2[idx2]);
}

// ---------------------------------------------------------------- K1: build X (bf16)
// X[row=(s,i,j)][n]: n<512 -> tw[s,q,n&1,n>>6] * (b_se[n] + sum_k rel[k]*W_se[n,k])
//                    n>=512 -> h[s*48+j][n-512]
// one wave per row, lane covers n = u*64+lane, u=0..8
__global__ __launch_bounds__(256) void k_build_x(const float* __restrict__ traj,
                                                 const float* __restrict__ tw,
                                                 const float* __restrict__ h,
                                                 const float* __restrict__ Wse,
                                                 const float* __restrict__ bse,
                                                 short* __restrict__ X) {
  int tid = threadIdx.x;
  int wid = tid >> 6, lane = tid & 63;
  int row = blockIdx.x * 4 + wid;
  int s   = row / (P_ * P_);
  int rem = row - s * (P_ * P_);
  int i   = rem / P_;
  int j   = rem - i * P_;
  int bi = s * P_ + i, bj = s * P_ + j;

  float rel[16];
#pragma unroll
  for (int t = 0; t < T_; ++t) {
    rel[t*2+0] = traj[(t*B_ + bj)*2 + 0] - traj[(t*B_ + bi)*2 + 0];
    rel[t*2+1] = traj[(t*B_ + bj)*2 + 1] - traj[(t*B_ + bi)*2 + 1];
  }
  const float* twq = tw + (size_t)(s * (P_*P_) + rem) * 16;  // [2][8] layout

#pragma unroll
  for (int u = 0; u < 9; ++u) {
    int n = u * 64 + lane;
    float val;
    if (n < KE_) {
      float acc = bse[n];
#pragma unroll
      for (int k = 0; k < 16; ++k) acc += rel[k] * Wse[n*16 + k];
      int t = n >> 6, c = n & 1;
      val = acc * twq[c*8 + t];
    } else {
      val = h[bj * H_ + (n - KE_)];
    }
    X[(size_t)row * K1_ + n] = f2bf(val);
  }
}

// ---------------------------------------------------------------- K2: GEMM1 + relu
// X1[73728x512] = relu(X[73728x576] @ W1b[512x576]^T + b1), bf16 out
// BM=128 BN=128 BK=64, 4 waves (2x2), wave tile 64x64 = 4x4 frags of 16x16x32
__global__ __launch_bounds__(256) void k_gemm1(const short* __restrict__ X,
                                               const short* __restrict__ W1b,
                                               const float* __restrict__ b1,
                                               short* __restrict__ X1) {
  __shared__ short At[128 * 64];
  __shared__ short Bt[128 * 64];
  int tid = threadIdx.x;
  int wid = tid >> 6, lane = tid & 63;
  int tm = blockIdx.x >> 2, tn = blockIdx.x & 3;
  int brow = tm * 128, bcol = tn * 128;
  int wr = wid >> 1, wc = wid & 1;
  int lr = lane & 15, lhi = lane >> 4;

  f32x4 acc[4][4];
#pragma unroll
  for (int m = 0; m < 4; ++m)
#pragma unroll
    for (int n = 0; n < 4; ++n) acc[m][n] = (f32x4){0.f, 0.f, 0.f, 0.f};

  for (int kt = 0; kt < K1_ / 64; ++kt) {
    int k0 = kt * 64;
#pragma unroll
    for (int it = 0; it < 4; ++it) {
      int flat = it * 2048 + tid * 8;          // element index in 128x64 tile
      int r = flat >> 6, c = flat & 63;
      async16(&X  [(size_t)(brow + r) * K1_ + k0 + c], &At[flat]);
      async16(&W1b[(size_t)(bcol + r) * K1_ + k0 + c], &Bt[flat]);
    }
    __syncthreads();                           // drains vmcnt before barrier
#pragma unroll
    for (int kk = 0; kk < 64; kk += 32) {
      short8 a[4], b[4];
#pragma unroll
      for (int m = 0; m < 4; ++m)
        a[m] = *(const short8*)&At[(wr*64 + m*16 + lr) * 64 + kk + lhi*8];
#pragma unroll
      for (int n = 0; n < 4; ++n)
        b[n] = *(const short8*)&Bt[(wc*64 + n*16 + lr) * 64 + kk + lhi*8];
#pragma unroll
      for (int m = 0; m < 4; ++m)
#pragma unroll
        for (int n = 0; n < 4; ++n)
          acc[m][n] = mfma16(a[m], b[n], acc[m][n]);
    }
    __syncthreads();
  }
  // epilogue: bias + relu, bf16 store. C/D: row=(lane>>4)*4+q, col=lane&15
#pragma unroll
  for (int n = 0; n < 4; ++n) {
    int gcol = bcol + wc*64 + n*16 + lr;
    float bias = b1[gcol];
#pragma unroll
    for (int m = 0; m < 4; ++m) {
      int grow0 = brow + wr*64 + m*16 + lhi*4;
#pragma unroll
      for (int q = 0; q < 4; ++q) {
        float v = acc[m][n][q] + bias;
        v = v > 0.f ? v : 0.f;
        X1[(size_t)(grow0 + q) * D1_ + gcol] = f2bf(v);
      }
    }
  }
}

// ---------------------------------------------------------------- K3: GEMM2 + relu + max over j
// BM=96 (2 j-groups of 48), BN=128, BK=64. Waves 2x2: wave rows wr*48..+48 = ONE group.
// Epilogue: per n-frag, max over 3 m-frags x 4 q regs, then shfl_xor(16),(32) -> group max.
__global__ __launch_bounds__(256) void k_gemm2(const short* __restrict__ X1,
                                               const short* __restrict__ W2b,
                                               const float* __restrict__ b2,
                                               float* __restrict__ out) {
  __shared__ short At[96 * 64];
  __shared__ short Bt[128 * 64];
  int tid = threadIdx.x;
  int wid = tid >> 6, lane = tid & 63;
  int tm = blockIdx.x >> 3, tn = blockIdx.x & 7;
  int brow = tm * 96, bcol = tn * 128;
  int wr = wid >> 1, wc = wid & 1;
  int lr = lane & 15, lhi = lane >> 4;

  f32x4 acc[3][4];
#pragma unroll
  for (int m = 0; m < 3; ++m)
#pragma unroll
    for (int n = 0; n < 4; ++n) acc[m][n] = (f32x4){0.f, 0.f, 0.f, 0.f};

  for (int kt = 0; kt < D1_ / 64; ++kt) {
    int k0 = kt * 64;
#pragma unroll
    for (int it = 0; it < 3; ++it) {          // A: 96x64 = 6144 elems = 3*256*8
      int flat = it * 2048 + tid * 8;
      int r = flat >> 6, c = flat & 63;
      async16(&X1[(size_t)(brow + r) * D1_ + k0 + c], &At[flat]);
    }
#pragma unroll
    for (int it = 0; it < 4; ++it) {          // B: 128x64
      int flat = it * 2048 + tid * 8;
      int r = flat >> 6, c = flat & 63;
      async16(&W2b[(size_t)(bcol + r) * D1_ + k0 + c], &Bt[flat]);
    }
    __syncthreads();
#pragma unroll
    for (int kk = 0; kk < 64; kk += 32) {
      short8 a[3], b[4];
#pragma unroll
      for (int m = 0; m < 3; ++m)
        a[m] = *(const short8*)&At[(wr*48 + m*16 + lr) * 64 + kk + lhi*8];
#pragma unroll
      for (int n = 0; n < 4; ++n)
        b[n] = *(const short8*)&Bt[(wc*64 + n*16 + lr) * 64 + kk + lhi*8];
#pragma unroll
      for (int m = 0; m < 3; ++m)
#pragma unroll
        for (int n = 0; n < 4; ++n)
          acc[m][n] = mfma16(a[m], b[n], acc[m][n]);
    }
    __syncthreads();
  }

  int g = tm * 2 + wr;                        // output row (s*48+i), in [0,1536)
#pragma unroll
  for (int n = 0; n < 4; ++n) {
    int gcol = bcol + wc*64 + n*16 + lr;
    float bias = b2[gcol];
    float r = 0.f;                            // relu floor == identity for max(relu(.))
#pragma unroll
    for (int m = 0; m < 3; ++m)
#pragma unroll
      for (int q = 0; q < 4; ++q) {
        float v = acc[m][n][q] + bias;
        if (v > r) r = v;
      }
    r = fmaxf(r, __shfl_xor(r, 16));
    r = fmaxf(r, __shfl_xor(r, 32));
    if (lhi == 0) out[(size_t)g * D2_ + gcol] = r;
  }
}

// ----------------------------------------------------------------
extern "C" void kernel_launch(void* const* d_in, const int* in_sizes, int n_in,
                              void* d_out, int out_size, void* d_ws, size_t ws_size,
                              hipStream_t stream) {
  const float* h_states = (const float*)d_in[0];
  // d_in[1] seq_start_end (uniform, unused), d_in[2] end_pos (unused),
  const float* traj = (const float*)d_in[3];
  const float* tw   = (const float*)d_in[4];
  // d_in[5] mlp_pre_pool_dim_0 (=512, unused)
  const float* Wse  = (const float*)d_in[6];
  const float* bse  = (const float*)d_in[7];
  const float* W1   = (const float*)d_in[8];
  const float* b1   = (const float*)d_in[9];
  const float* W2   = (const float*)d_in[10];
  const float* b2   = (const float*)d_in[11];
  float* out = (float*)d_out;

  // workspace layout (all 16B aligned)
  char* ws = (char*)d_ws;
  const size_t X_BYTES  = (size_t)M_ * K1_ * 2;   // 84,934,656
  const size_t X1_BYTES = (size_t)M_ * D1_ * 2;   // 75,497,472
  const size_t W1B_BYTES = (size_t)D1_ * K1_ * 2; //    589,824
  short* X   = (short*)ws;
  short* X1  = (short*)(ws + X_BYTES);
  short* W1b = (short*)(ws + X_BYTES + X1_BYTES);
  short* W2b = (short*)(ws + X_BYTES + X1_BYTES + W1B_BYTES);
  // total ~162.1 MB required of ws_size

  k_cvt_w  <<<(D1_*K1_ + D2_*D1_ + 255) / 256, 256, 0, stream>>>(W1, W2, W1b, W2b);
  k_build_x<<<M_ / 4, 256, 0, stream>>>(traj, tw, h_states, Wse, bse, X);
  k_gemm1  <<<(M_ / 128) * (D1_ / 128), 256, 0, stream>>>(X, W1b, b1, X1);
  k_gemm2  <<<(M_ / 96) * (D2_ / 128), 256, 0, stream>>>(X1, W2b, b2, out);
}

// Round 2
// 306.643 us; speedup vs baseline: 1.4559x; 1.4559x over previous
//
#include <hip/hip_runtime.h>
#include <hip/hip_bf16.h>
#include <stdint.h>

// Problem constants (from reference)
#define S_  32
#define P_  48
#define T_  8
#define E_  64
#define H_  64
#define D1_ 512
#define D2_ 1024
#define B_  (S_*P_)        // 1536
#define M_  (S_*P_*P_)     // 73728 rows of the big GEMMs
#define K1_ 576            // T*E + H
#define KE_ 512            // T*E

typedef __attribute__((ext_vector_type(8))) short  short8;
typedef __attribute__((ext_vector_type(8))) __bf16 bf16x8;
typedef __attribute__((ext_vector_type(4))) float  f32x4;
typedef __attribute__((ext_vector_type(8))) float  f32x8;

// fp32 -> bf16 (round to nearest even), bit carrier = short
__device__ inline short f2bf(float x) {
  union { float f; unsigned u; } v; v.f = x;
  unsigned r = v.u + 0x7FFFu + ((v.u >> 16) & 1u);
  return (short)(r >> 16);
}

// async global->LDS, 16 bytes per lane (wave-uniform base + lane*16 pattern)
__device__ inline void async16(const void* g, void* l) {
  __builtin_amdgcn_global_load_lds(
      (const __attribute__((address_space(1))) void*)g,
      (__attribute__((address_space(3))) void*)l, 16, 0, 0);
}

__device__ inline f32x4 mfma16(short8 a, short8 b, f32x4 c) {
  return __builtin_amdgcn_mfma_f32_16x16x32_bf16(
      __builtin_bit_cast(bf16x8, a), __builtin_bit_cast(bf16x8, b), c, 0, 0, 0);
}

// ---------------------------------------------------------------- K0: weights -> bf16
__global__ __launch_bounds__(256) void k_cvt_w(const float* __restrict__ W1,
                                               const float* __restrict__ W2,
                                               short* __restrict__ W1b,
                                               short* __restrict__ W2b) {
  int idx = blockIdx.x * 256 + threadIdx.x;
  if (idx < D1_ * K1_) W1b[idx] = f2bf(W1[idx]);
  int idx2 = idx - D1_ * K1_;
  if (idx2 >= 0 && idx2 < D2_ * D1_) W2b[idx2] = f2bf(W2[idx2]);
}

// ---------------------------------------------------------------- K0b: oW[p][n] = obs[p] @ Wse^T  (fp32)
// obs_flat[p][k=t*2+c] = traj[(t*B+p)*2+c]; 1536x512, K=16
__global__ __launch_bounds__(256) void k_oW(const float* __restrict__ traj,
                                            const float* __restrict__ Wse,
                                            float* __restrict__ oW) {
  int bid = blockIdx.x;                 // 1536*2 blocks
  int p = bid >> 1;
  int n = ((bid & 1) << 8) + threadIdx.x;
  float obs[16];
#pragma unroll
  for (int t = 0; t < T_; ++t) {
    obs[2*t]   = traj[(t*B_ + p)*2 + 0];
    obs[2*t+1] = traj[(t*B_ + p)*2 + 1];
  }
  float acc = 0.f;
#pragma unroll
  for (int k = 0; k < 16; ++k) acc += obs[k] * Wse[n*16 + k];
  oW[p*KE_ + n] = acc;
}

// ---------------------------------------------------------------- K1: build X (bf16)
// X[row=(s,i,j)][n<512]  = tw[s,rem,n&1,n>>6] * (oW[bj][n] - oW[bi][n] + bse[n])
// X[row][n>=512]         = h[bj][n-512]
// one wave per row; lane handles n = lane*8 .. +8 (f32x8 loads, short8 store)
__global__ __launch_bounds__(256) void k_build_x(const float* __restrict__ tw,
                                                 const float* __restrict__ h,
                                                 const float* __restrict__ bse,
                                                 const float* __restrict__ oW,
                                                 short* __restrict__ X) {
  int tid = threadIdx.x;
  int wid = tid >> 6, lane = tid & 63;
  int row = blockIdx.x * 4 + wid;
  int s   = row / (P_ * P_);
  int rem = row - s * (P_ * P_);
  int i   = rem / P_;
  int j   = rem - i * P_;
  int bi = s * P_ + i, bj = s * P_ + j;

  const float* twq = tw + (size_t)(s * (P_*P_) + rem) * 16;  // [2][8]
  int t = lane >> 3;                 // n>>6 for this lane's 8-elem chunk
  float w0 = twq[t];                 // c = 0 (even n)
  float w1 = twq[8 + t];             // c = 1 (odd n)

  int n0 = lane * 8;
  f32x8 vj = *(const f32x8*)&oW[(size_t)bj * KE_ + n0];
  f32x8 vi = *(const f32x8*)&oW[(size_t)bi * KE_ + n0];
  f32x8 vb = *(const f32x8*)&bse[n0];
  short8 o;
#pragma unroll
  for (int k = 0; k < 8; ++k) {
    float e = (vj[k] - vi[k] + vb[k]) * ((k & 1) ? w1 : w0);
    o[k] = f2bf(e);
  }
  *(short8*)&X[(size_t)row * K1_ + n0] = o;

  if (lane < 8) {                    // h tail: 64 elems = 8 lanes x short8
    f32x8 vh = *(const f32x8*)&h[(size_t)bj * H_ + lane * 8];
    short8 oh;
#pragma unroll
    for (int k = 0; k < 8; ++k) oh[k] = f2bf(vh[k]);
    *(short8*)&X[(size_t)row * K1_ + KE_ + lane * 8] = oh;
  }
}

// ---------------------------------------------------------------- K2: GEMM1 + relu
// X1[73728x512] = relu(X[73728x576] @ W1b[512x576]^T + b1), bf16 out
// BM=128 BN=128 BK=64, 4 waves (2x2), wave tile 64x64 = 4x4 frags of 16x16x32
__global__ __launch_bounds__(256) void k_gemm1(const short* __restrict__ X,
                                               const short* __restrict__ W1b,
                                               const float* __restrict__ b1,
                                               short* __restrict__ X1) {
  __shared__ short At[128 * 64];
  __shared__ short Bt[128 * 64];
  int tid = threadIdx.x;
  int wid = tid >> 6, lane = tid & 63;
  int tm = blockIdx.x >> 2, tn = blockIdx.x & 3;
  int brow = tm * 128, bcol = tn * 128;
  int wr = wid >> 1, wc = wid & 1;
  int lr = lane & 15, lhi = lane >> 4;

  f32x4 acc[4][4];
#pragma unroll
  for (int m = 0; m < 4; ++m)
#pragma unroll
    for (int n = 0; n < 4; ++n) acc[m][n] = (f32x4){0.f, 0.f, 0.f, 0.f};

  for (int kt = 0; kt < K1_ / 64; ++kt) {
    int k0 = kt * 64;
#pragma unroll
    for (int it = 0; it < 4; ++it) {
      int flat = it * 2048 + tid * 8;          // element index in 128x64 tile
      int r = flat >> 6, c = flat & 63;
      async16(&X  [(size_t)(brow + r) * K1_ + k0 + c], &At[flat]);
      async16(&W1b[(size_t)(bcol + r) * K1_ + k0 + c], &Bt[flat]);
    }
    __syncthreads();                           // drains vmcnt before barrier
#pragma unroll
    for (int kk = 0; kk < 64; kk += 32) {
      short8 a[4], b[4];
#pragma unroll
      for (int m = 0; m < 4; ++m)
        a[m] = *(const short8*)&At[(wr*64 + m*16 + lr) * 64 + kk + lhi*8];
#pragma unroll
      for (int n = 0; n < 4; ++n)
        b[n] = *(const short8*)&Bt[(wc*64 + n*16 + lr) * 64 + kk + lhi*8];
#pragma unroll
      for (int m = 0; m < 4; ++m)
#pragma unroll
        for (int n = 0; n < 4; ++n)
          acc[m][n] = mfma16(a[m], b[n], acc[m][n]);
    }
    __syncthreads();
  }
  // epilogue: bias + relu, bf16 store. C/D: row=(lane>>4)*4+q, col=lane&15
#pragma unroll
  for (int n = 0; n < 4; ++n) {
    int gcol = bcol + wc*64 + n*16 + lr;
    float bias = b1[gcol];
#pragma unroll
    for (int m = 0; m < 4; ++m) {
      int grow0 = brow + wr*64 + m*16 + lhi*4;
#pragma unroll
      for (int q = 0; q < 4; ++q) {
        float v = acc[m][n][q] + bias;
        v = v > 0.f ? v : 0.f;
        X1[(size_t)(grow0 + q) * D1_ + gcol] = f2bf(v);
      }
    }
  }
}

// ---------------------------------------------------------------- K3: GEMM2 + relu + max over j
// BM=96 (2 j-groups of 48), BN=128, BK=64. Waves 2x2: wave rows wr*48..+48 = ONE group.
// Epilogue: per n-frag, max over 3 m-frags x 4 q regs, then shfl_xor(16),(32) -> group max.
__global__ __launch_bounds__(256) void k_gemm2(const short* __restrict__ X1,
                                               const short* __restrict__ W2b,
                                               const float* __restrict__ b2,
                                               float* __restrict__ out) {
  __shared__ short At[96 * 64];
  __shared__ short Bt[128 * 64];
  int tid = threadIdx.x;
  int wid = tid >> 6, lane = tid & 63;
  int tm = blockIdx.x >> 3, tn = blockIdx.x & 7;
  int brow = tm * 96, bcol = tn * 128;
  int wr = wid >> 1, wc = wid & 1;
  int lr = lane & 15, lhi = lane >> 4;

  f32x4 acc[3][4];
#pragma unroll
  for (int m = 0; m < 3; ++m)
#pragma unroll
    for (int n = 0; n < 4; ++n) acc[m][n] = (f32x4){0.f, 0.f, 0.f, 0.f};

  for (int kt = 0; kt < D1_ / 64; ++kt) {
    int k0 = kt * 64;
#pragma unroll
    for (int it = 0; it < 3; ++it) {          // A: 96x64 = 6144 elems = 3*256*8
      int flat = it * 2048 + tid * 8;
      int r = flat >> 6, c = flat & 63;
      async16(&X1[(size_t)(brow + r) * D1_ + k0 + c], &At[flat]);
    }
#pragma unroll
    for (int it = 0; it < 4; ++it) {          // B: 128x64
      int flat = it * 2048 + tid * 8;
      int r = flat >> 6, c = flat & 63;
      async16(&W2b[(size_t)(bcol + r) * D1_ + k0 + c], &Bt[flat]);
    }
    __syncthreads();
#pragma unroll
    for (int kk = 0; kk < 64; kk += 32) {
      short8 a[3], b[4];
#pragma unroll
      for (int m = 0; m < 3; ++m)
        a[m] = *(const short8*)&At[(wr*48 + m*16 + lr) * 64 + kk + lhi*8];
#pragma unroll
      for (int n = 0; n < 4; ++n)
        b[n] = *(const short8*)&Bt[(wc*64 + n*16 + lr) * 64 + kk + lhi*8];
#pragma unroll
      for (int m = 0; m < 3; ++m)
#pragma unroll
        for (int n = 0; n < 4; ++n)
          acc[m][n] = mfma16(a[m], b[n], acc[m][n]);
    }
    __syncthreads();
  }

  int g = tm * 2 + wr;                        // output row (s*48+i), in [0,1536)
#pragma unroll
  for (int n = 0; n < 4; ++n) {
    int gcol = bcol + wc*64 + n*16 + lr;
    float bias = b2[gcol];
    float r = 0.f;                            // relu floor == identity for max(relu(.))
#pragma unroll
    for (int m = 0; m < 3; ++m)
#pragma unroll
      for (int q = 0; q < 4; ++q) {
        float v = acc[m][n][q] + bias;
        if (v > r) r = v;
      }
    r = fmaxf(r, __shfl_xor(r, 16));
    r = fmaxf(r, __shfl_xor(r, 32));
    if (lhi == 0) out[(size_t)g * D2_ + gcol] = r;
  }
}

// ----------------------------------------------------------------
extern "C" void kernel_launch(void* const* d_in, const int* in_sizes, int n_in,
                              void* d_out, int out_size, void* d_ws, size_t ws_size,
                              hipStream_t stream) {
  const float* h_states = (const float*)d_in[0];
  // d_in[1] seq_start_end (uniform, unused), d_in[2] end_pos (unused),
  const float* traj = (const float*)d_in[3];
  const float* tw   = (const float*)d_in[4];
  // d_in[5] mlp_pre_pool_dim_0 (=512, unused)
  const float* Wse  = (const float*)d_in[6];
  const float* bse  = (const float*)d_in[7];
  const float* W1   = (const float*)d_in[8];
  const float* b1   = (const float*)d_in[9];
  const float* W2   = (const float*)d_in[10];
  const float* b2   = (const float*)d_in[11];
  float* out = (float*)d_out;

  // workspace layout (all 16B aligned)
  char* ws = (char*)d_ws;
  const size_t X_BYTES   = (size_t)M_ * K1_ * 2;   // 84,934,656
  const size_t X1_BYTES  = (size_t)M_ * D1_ * 2;   // 75,497,472
  const size_t W1B_BYTES = (size_t)D1_ * K1_ * 2;  //    589,824
  short* X   = (short*)ws;
  short* X1  = (short*)(ws + X_BYTES);
  short* W1b = (short*)(ws + X_BYTES + X1_BYTES);
  short* W2b = (short*)(ws + X_BYTES + X1_BYTES + W1B_BYTES);
  // oW (1536x512 fp32 = 3 MB) aliases the head of X1: consumed by k_build_x
  // BEFORE k_gemm1 writes X1 (same-stream ordering). Zero extra ws needed.
  float* oW  = (float*)(ws + X_BYTES);

  k_cvt_w  <<<(D1_*K1_ + D2_*D1_ + 255) / 256, 256, 0, stream>>>(W1, W2, W1b, W2b);
  k_oW     <<<B_ * 2, 256, 0, stream>>>(traj, Wse, oW);
  k_build_x<<<M_ / 4, 256, 0, stream>>>(tw, h_states, bse, oW, X);
  k_gemm1  <<<(M_ / 128) * (D1_ / 128), 256, 0, stream>>>(X, W1b, b1, X1);
  k_gemm2  <<<(M_ / 96) * (D2_ / 128), 256, 0, stream>>>(X1, W2b, b2, out);
}

// Round 3
// 255.169 us; speedup vs baseline: 1.7496x; 1.2017x over previous
//
#include <hip/hip_runtime.h>
#include <hip/hip_bf16.h>
#include <stdint.h>

// Problem constants (from reference)
#define S_  32
#define P_  48
#define T_  8
#define E_  64
#define H_  64
#define D1_ 512
#define D2_ 1024
#define B_  (S_*P_)        // 1536
#define M_  (S_*P_*P_)     // 73728 rows of the big GEMMs
#define K1_ 576            // T*E + H
#define KE_ 512            // T*E

typedef __attribute__((ext_vector_type(8))) short  short8;
typedef __attribute__((ext_vector_type(8))) __bf16 bf16x8;
typedef __attribute__((ext_vector_type(4))) float  f32x4;
typedef __attribute__((ext_vector_type(8))) float  f32x8;

// fp32 -> bf16 (round to nearest even), bit carrier = short
__device__ inline short f2bf(float x) {
  union { float f; unsigned u; } v; v.f = x;
  unsigned r = v.u + 0x7FFFu + ((v.u >> 16) & 1u);
  return (short)(r >> 16);
}

// async global->LDS, 16 bytes per lane (wave-uniform LDS base + lane*16; the
// GLOBAL source address is per-lane -> T2 swizzle done by pre-swizzling source)
__device__ inline void async16(const void* g, void* l) {
  __builtin_amdgcn_global_load_lds(
      (const __attribute__((address_space(1))) void*)g,
      (__attribute__((address_space(3))) void*)l, 16, 0, 0);
}

__device__ inline f32x4 mfma16(short8 a, short8 b, f32x4 c) {
  return __builtin_amdgcn_mfma_f32_16x16x32_bf16(
      __builtin_bit_cast(bf16x8, a), __builtin_bit_cast(bf16x8, b), c, 0, 0, 0);
}

// ---------------------------------------------------------------- K0: weights -> bf16
__global__ __launch_bounds__(256) void k_cvt_w(const float* __restrict__ W1,
                                               const float* __restrict__ W2,
                                               short* __restrict__ W1b,
                                               short* __restrict__ W2b) {
  int idx = blockIdx.x * 256 + threadIdx.x;
  if (idx < D1_ * K1_) W1b[idx] = f2bf(W1[idx]);
  int idx2 = idx - D1_ * K1_;
  if (idx2 >= 0 && idx2 < D2_ * D1_) W2b[idx2] = f2bf(W2[idx2]);
}

// ---------------------------------------------------------------- K0b: oW[p][n] = obs[p] @ Wse^T  (fp32)
__global__ __launch_bounds__(256) void k_oW(const float* __restrict__ traj,
                                            const float* __restrict__ Wse,
                                            float* __restrict__ oW) {
  int bid = blockIdx.x;                 // 1536*2 blocks
  int p = bid >> 1;
  int n = ((bid & 1) << 8) + threadIdx.x;
  float obs[16];
#pragma unroll
  for (int t = 0; t < T_; ++t) {
    obs[2*t]   = traj[(t*B_ + p)*2 + 0];
    obs[2*t+1] = traj[(t*B_ + p)*2 + 1];
  }
  float acc = 0.f;
#pragma unroll
  for (int k = 0; k < 16; ++k) acc += obs[k] * Wse[n*16 + k];
  oW[p*KE_ + n] = acc;
}

// ---------------------------------------------------------------- K1: build X (bf16)
// X[row=(s,i,j)][n<512]  = tw[s,rem,n&1,n>>6] * (oW[bj][n] - oW[bi][n] + bse[n])
// X[row][n>=512]         = h[bj][n-512]
__global__ __launch_bounds__(256) void k_build_x(const float* __restrict__ tw,
                                                 const float* __restrict__ h,
                                                 const float* __restrict__ bse,
                                                 const float* __restrict__ oW,
                                                 short* __restrict__ X) {
  int tid = threadIdx.x;
  int wid = tid >> 6, lane = tid & 63;
  int row = blockIdx.x * 4 + wid;
  int s   = row / (P_ * P_);
  int rem = row - s * (P_ * P_);
  int i   = rem / P_;
  int j   = rem - i * P_;
  int bi = s * P_ + i, bj = s * P_ + j;

  const float* twq = tw + (size_t)(s * (P_*P_) + rem) * 16;  // [2][8]
  int t = lane >> 3;                 // n>>6 for this lane's 8-elem chunk
  float w0 = twq[t];                 // c = 0 (even n)
  float w1 = twq[8 + t];             // c = 1 (odd n)

  int n0 = lane * 8;
  f32x8 vj = *(const f32x8*)&oW[(size_t)bj * KE_ + n0];
  f32x8 vi = *(const f32x8*)&oW[(size_t)bi * KE_ + n0];
  f32x8 vb = *(const f32x8*)&bse[n0];
  short8 o;
#pragma unroll
  for (int k = 0; k < 8; ++k) {
    float e = (vj[k] - vi[k] + vb[k]) * ((k & 1) ? w1 : w0);
    o[k] = f2bf(e);
  }
  *(short8*)&X[(size_t)row * K1_ + n0] = o;

  if (lane < 8) {                    // h tail: 64 elems = 8 lanes x short8
    f32x8 vh = *(const f32x8*)&h[(size_t)bj * H_ + lane * 8];
    short8 oh;
#pragma unroll
    for (int k = 0; k < 8; ++k) oh[k] = f2bf(vh[k]);
    *(short8*)&X[(size_t)row * K1_ + KE_ + lane * 8] = oh;
  }
}

// ---------------------------------------------------------------- K2: GEMM1 + relu
// X1 = relu(X[73728x576] @ W1b[512x576]^T + b1), bf16 out
// BM=128 BN=128 BK=64; min-2-phase dbuf; T2 swizzled LDS; T1 XCD swizzle.
__global__ __launch_bounds__(256) void k_gemm1(const short* __restrict__ X,
                                               const short* __restrict__ W1b,
                                               const float* __restrict__ b1,
                                               short* __restrict__ X1) {
  __shared__ short Ae[128*64], Ao[128*64], Be[128*64], Bo[128*64];
  int tid = threadIdx.x;
  int wid = tid >> 6, lane = tid & 63;
  // T1: same-tm blocks (tn=0..3) -> same XCD (grid 2304 = 8*288)
  int wgid = (blockIdx.x & 7) * (2304/8) + (blockIdx.x >> 3);
  int tm = wgid >> 2, tn = wgid & 3;
  int brow = tm * 128, bcol = tn * 128;
  int wr = wid >> 1, wc = wid & 1;
  int lr = lane & 15, lhi = lane >> 4;
  int sx = lr & 7;                    // T2 read-side XOR (row&7 == lr&7 here)

  f32x4 acc[4][4];
#pragma unroll
  for (int m = 0; m < 4; ++m)
#pragma unroll
    for (int n = 0; n < 4; ++n) acc[m][n] = (f32x4){0.f, 0.f, 0.f, 0.f};

  // stage: source col pre-swizzled (g ^ (r&7)), LDS dest linear
  auto stage = [&](short* Ab, short* Bb, int k0) {
#pragma unroll
    for (int it = 0; it < 4; ++it) {
      int fg = it * 256 + tid;        // 16B-granule id in 128x64 tile
      int r = fg >> 3, gs = (fg & 7) ^ (r & 7);
      async16(&X  [(size_t)(brow + r) * K1_ + k0 + (gs << 3)], &Ab[fg * 8]);
    }
#pragma unroll
    for (int it = 0; it < 4; ++it) {
      int fg = it * 256 + tid;
      int r = fg >> 3, gs = (fg & 7) ^ (r & 7);
      async16(&W1b[(size_t)(bcol + r) * K1_ + k0 + (gs << 3)], &Bb[fg * 8]);
    }
  };
  auto compute = [&](const short* Ab, const short* Bb) {
#pragma unroll
    for (int kk = 0; kk < 64; kk += 32) {
      int gr = (kk >> 3) + lhi;
      short8 a[4], b[4];
#pragma unroll
      for (int m = 0; m < 4; ++m)
        a[m] = *(const short8*)&Ab[(wr*64 + m*16 + lr) * 64 + ((gr ^ sx) << 3)];
#pragma unroll
      for (int n = 0; n < 4; ++n)
        b[n] = *(const short8*)&Bb[(wc*64 + n*16 + lr) * 64 + ((gr ^ sx) << 3)];
#pragma unroll
      for (int m = 0; m < 4; ++m)
#pragma unroll
        for (int n = 0; n < 4; ++n)
          acc[m][n] = mfma16(a[m], b[n], acc[m][n]);
    }
  };

  // K1_/64 = 9 tiles: prologue + 4x(even,odd) + final even compute
  stage(Ae, Be, 0);
  __syncthreads();
  for (int ktp = 0; ktp < 4; ++ktp) {
    stage(Ao, Bo, ktp*128 + 64);      // issue BEFORE compute -> overlap
    compute(Ae, Be);
    __syncthreads();                  // one barrier per tile (drains vm+lgkm)
    stage(Ae, Be, ktp*128 + 128);
    compute(Ao, Bo);
    __syncthreads();
  }
  compute(Ae, Be);                    // kt = 8

  // epilogue: bias + relu, bf16 store. C/D: row=(lane>>4)*4+q, col=lane&15
#pragma unroll
  for (int n = 0; n < 4; ++n) {
    int gcol = bcol + wc*64 + n*16 + lr;
    float bias = b1[gcol];
#pragma unroll
    for (int m = 0; m < 4; ++m) {
      int grow0 = brow + wr*64 + m*16 + lhi*4;
#pragma unroll
      for (int q = 0; q < 4; ++q) {
        float v = acc[m][n][q] + bias;
        v = v > 0.f ? v : 0.f;
        X1[(size_t)(grow0 + q) * D1_ + gcol] = f2bf(v);
      }
    }
  }
}

// ---------------------------------------------------------------- K3: GEMM2 + relu + max over j
// BM=96 (2 j-groups), BN=128; min-2-phase dbuf; T2 swizzle; T1 XCD swizzle.
__global__ __launch_bounds__(256) void k_gemm2(const short* __restrict__ X1,
                                               const short* __restrict__ W2b,
                                               const float* __restrict__ b2,
                                               float* __restrict__ out) {
  __shared__ short Ae[96*64], Ao[96*64], Be[128*64], Bo[128*64];
  int tid = threadIdx.x;
  int wid = tid >> 6, lane = tid & 63;
  // T1: same-tm blocks (tn=0..7) -> same XCD (grid 6144 = 8*768)
  int wgid = (blockIdx.x & 7) * (6144/8) + (blockIdx.x >> 3);
  int tm = wgid >> 3, tn = wgid & 7;
  int brow = tm * 96, bcol = tn * 128;
  int wr = wid >> 1, wc = wid & 1;
  int lr = lane & 15, lhi = lane >> 4;
  int sx = lr & 7;

  f32x4 acc[3][4];
#pragma unroll
  for (int m = 0; m < 3; ++m)
#pragma unroll
    for (int n = 0; n < 4; ++n) acc[m][n] = (f32x4){0.f, 0.f, 0.f, 0.f};

  auto stage = [&](short* Ab, short* Bb, int k0) {
#pragma unroll
    for (int it = 0; it < 3; ++it) {  // A: 96x64 = 768 granules
      int fg = it * 256 + tid;
      int r = fg >> 3, gs = (fg & 7) ^ (r & 7);
      async16(&X1 [(size_t)(brow + r) * D1_ + k0 + (gs << 3)], &Ab[fg * 8]);
    }
#pragma unroll
    for (int it = 0; it < 4; ++it) {  // B: 128x64 = 1024 granules
      int fg = it * 256 + tid;
      int r = fg >> 3, gs = (fg & 7) ^ (r & 7);
      async16(&W2b[(size_t)(bcol + r) * D1_ + k0 + (gs << 3)], &Bb[fg * 8]);
    }
  };
  auto compute = [&](const short* Ab, const short* Bb) {
#pragma unroll
    for (int kk = 0; kk < 64; kk += 32) {
      int gr = (kk >> 3) + lhi;
      short8 a[3], b[4];
#pragma unroll
      for (int m = 0; m < 3; ++m)
        a[m] = *(const short8*)&Ab[(wr*48 + m*16 + lr) * 64 + ((gr ^ sx) << 3)];
#pragma unroll
      for (int n = 0; n < 4; ++n)
        b[n] = *(const short8*)&Bb[(wc*64 + n*16 + lr) * 64 + ((gr ^ sx) << 3)];
#pragma unroll
      for (int m = 0; m < 3; ++m)
#pragma unroll
        for (int n = 0; n < 4; ++n)
          acc[m][n] = mfma16(a[m], b[n], acc[m][n]);
    }
  };

  // D1_/64 = 8 tiles: prologue + 4x(even,odd), last odd stages nothing
  stage(Ae, Be, 0);
  __syncthreads();
  for (int ktp = 0; ktp < 4; ++ktp) {
    stage(Ao, Bo, ktp*128 + 64);
    compute(Ae, Be);
    __syncthreads();
    if (ktp < 3) stage(Ae, Be, ktp*128 + 128);
    compute(Ao, Bo);
    __syncthreads();
  }

  int g = tm * 2 + wr;                // output row (s*48+i)
#pragma unroll
  for (int n = 0; n < 4; ++n) {
    int gcol = bcol + wc*64 + n*16 + lr;
    float bias = b2[gcol];
    float r = 0.f;                    // relu floor == identity for max(relu(.))
#pragma unroll
    for (int m = 0; m < 3; ++m)
#pragma unroll
      for (int q = 0; q < 4; ++q) {
        float v = acc[m][n][q] + bias;
        if (v > r) r = v;
      }
    r = fmaxf(r, __shfl_xor(r, 16));
    r = fmaxf(r, __shfl_xor(r, 32));
    if (lhi == 0) out[(size_t)g * D2_ + gcol] = r;
  }
}

// ----------------------------------------------------------------
extern "C" void kernel_launch(void* const* d_in, const int* in_sizes, int n_in,
                              void* d_out, int out_size, void* d_ws, size_t ws_size,
                              hipStream_t stream) {
  const float* h_states = (const float*)d_in[0];
  const float* traj = (const float*)d_in[3];
  const float* tw   = (const float*)d_in[4];
  const float* Wse  = (const float*)d_in[6];
  const float* bse  = (const float*)d_in[7];
  const float* W1   = (const float*)d_in[8];
  const float* b1   = (const float*)d_in[9];
  const float* W2   = (const float*)d_in[10];
  const float* b2   = (const float*)d_in[11];
  float* out = (float*)d_out;

  char* ws = (char*)d_ws;
  const size_t X_BYTES   = (size_t)M_ * K1_ * 2;   // 84,934,656
  const size_t X1_BYTES  = (size_t)M_ * D1_ * 2;   // 75,497,472
  const size_t W1B_BYTES = (size_t)D1_ * K1_ * 2;  //    589,824
  short* X   = (short*)ws;
  short* X1  = (short*)(ws + X_BYTES);
  short* W1b = (short*)(ws + X_BYTES + X1_BYTES);
  short* W2b = (short*)(ws + X_BYTES + X1_BYTES + W1B_BYTES);
  // oW (3 MB fp32) aliases head of X1: consumed by k_build_x before k_gemm1
  float* oW  = (float*)(ws + X_BYTES);

  k_cvt_w  <<<(D1_*K1_ + D2_*D1_ + 255) / 256, 256, 0, stream>>>(W1, W2, W1b, W2b);
  k_oW     <<<B_ * 2, 256, 0, stream>>>(traj, Wse, oW);
  k_build_x<<<M_ / 4, 256, 0, stream>>>(tw, h_states, bse, oW, X);
  k_gemm1  <<<(M_ / 128) * (D1_ / 128), 256, 0, stream>>>(X, W1b, b1, X1);
  k_gemm2  <<<(M_ / 96) * (D2_ / 128), 256, 0, stream>>>(X1, W2b, b2, out);
}